// Round 3
// baseline (1829.177 us; speedup 1.0000x reference)
//
#include <hip/hip_runtime.h>
#include <hip/hip_bf16.h>
#include <cstdint>
#include <cstddef>

#define B_ 64
#define T_ 2048
#define D_ 256
#define H_ 256

__device__ __forceinline__ float sigmoidf_(float x){ return 1.f/(1.f+__expf(-x)); }
__device__ __forceinline__ float tanhf_(float x){
  x = fminf(fmaxf(x,-15.f),15.f);
  float e = __expf(2.f*x);
  return (e-1.f)/(e+1.f);
}
__device__ __forceinline__ float sane(float x){
  return (fabsf(x) < 3.0e38f) ? x : 0.f;   // non-finite -> 0 (diagnostic shield)
}

// 64x64 tile, 3 gate accumulators, K-chunk = 32, tiles k-major: As[k][m], B*[k][n]
__device__ __forceinline__ void mma_chunk(int tid,
    const float (*As)[64], const float (*B0)[64], const float (*B1)[64], const float (*B2)[64],
    float (&aR)[4][4], float (&aZ)[4][4], float (&aN)[4][4])
{
  const int m0=(tid>>4)<<2, n0=(tid&15)<<2;
  #pragma unroll
  for(int k=0;k<32;k++){
    const float4 a =*(const float4*)&As[k][m0];
    const float4 br=*(const float4*)&B0[k][n0];
    const float4 bz=*(const float4*)&B1[k][n0];
    const float4 bn=*(const float4*)&B2[k][n0];
    const float am[4]={a.x,a.y,a.z,a.w};
    const float r4[4]={br.x,br.y,br.z,br.w};
    const float z4[4]={bz.x,bz.y,bz.z,bz.w};
    const float n4[4]={bn.x,bn.y,bn.z,bn.w};
    #pragma unroll
    for(int i=0;i<4;i++){
      #pragma unroll
      for(int j=0;j<4;j++){
        aR[i][j]=fmaf(am[i],r4[j],aR[i][j]);
        aZ[i][j]=fmaf(am[i],z4[j],aZ[i][j]);
        aN[i][j]=fmaf(am[i],n4[j],aN[i][j]);
      }
    }
  }
}

// rel_table[r][j] = rel_emb[r] . rel_w_ih[j] + rel_b_ih[j], r<64, j<768
__global__ __launch_bounds__(256)
void table_kernel(const float* __restrict__ rel_emb, const float* __restrict__ w_ih,
                  const float* __restrict__ b_ih, float* __restrict__ table)
{
  int idx = blockIdx.x*256 + threadIdx.x;   // < 64*768
  int r = idx/768, j = idx - r*768;
  const float* e = rel_emb + (size_t)r*256;
  const float* w = w_ih   + (size_t)j*256;
  float acc = 0.f;
  for(int k=0;k<256;k+=4){
    float4 ev = *(const float4*)(e+k);
    float4 wv = *(const float4*)(w+k);
    acc = fmaf(ev.x,wv.x,acc); acc = fmaf(ev.y,wv.y,acc);
    acc = fmaf(ev.z,wv.z,acc); acc = fmaf(ev.w,wv.w,acc);
  }
  table[idx] = acc + b_ih[j];
}

// h[b,t] = GRU_node(x=embs[b,t], hidden=red[b,t]) for t in [t_lo, t_lo+cnt)
// grid = (cnt, 4): blockIdx.x = 64-row tile of M=64*cnt rows, blockIdx.y = 64-col tile
template<bool LEAF>
__global__ __launch_bounds__(256)
void node_kernel(const float* __restrict__ embs, const float* __restrict__ red,
                 const float* __restrict__ w_ih, const float* __restrict__ w_hh,
                 const float* __restrict__ b_ih, const float* __restrict__ b_hh,
                 float* __restrict__ out, int t_lo, int cnt)
{
  __shared__ float As[32][64];
  __shared__ float B0[32][64], B1[32][64], B2[32][64];
  const int tid = threadIdx.x;
  const int mt = blockIdx.x, nt = blockIdx.y;

  const int sm = tid>>2;          // staged row 0..63
  const int sk = (tid&3)<<3;      // staged k-offset {0,8,16,24}
  const int gm = mt*64 + sm;
  const int sb = gm / cnt;
  const int st = t_lo + (gm - sb*cnt);
  const float* xrow = embs + ((size_t)sb*T_ + st)*D_;
  const float* rrow = red  + ((size_t)sb*256 + st)*256;   // deref only when !LEAF (t<256)
  const size_t wrow = ((size_t)(nt*64) + sm)*256;         // W row for gate r; +65536/+131072 for z/n

  float aR[4][4]={}, aZ[4][4]={}, aN1[4][4]={}, aN2[4][4]={};

  // pass 1: gates += x @ W_ih^T
  #pragma unroll 1
  for(int kk=0; kk<256; kk+=32){
    float4 a0 = *(const float4*)(xrow + kk + sk);
    float4 a1 = *(const float4*)(xrow + kk + sk + 4);
    float4 p0 = *(const float4*)(w_ih + wrow          + kk + sk);
    float4 p1 = *(const float4*)(w_ih + wrow          + kk + sk + 4);
    float4 q0 = *(const float4*)(w_ih + wrow +  65536 + kk + sk);
    float4 q1 = *(const float4*)(w_ih + wrow +  65536 + kk + sk + 4);
    float4 r0 = *(const float4*)(w_ih + wrow + 131072 + kk + sk);
    float4 r1 = *(const float4*)(w_ih + wrow + 131072 + kk + sk + 4);
    __syncthreads();
    As[sk+0][sm]=a0.x; As[sk+1][sm]=a0.y; As[sk+2][sm]=a0.z; As[sk+3][sm]=a0.w;
    As[sk+4][sm]=a1.x; As[sk+5][sm]=a1.y; As[sk+6][sm]=a1.z; As[sk+7][sm]=a1.w;
    B0[sk+0][sm]=p0.x; B0[sk+1][sm]=p0.y; B0[sk+2][sm]=p0.z; B0[sk+3][sm]=p0.w;
    B0[sk+4][sm]=p1.x; B0[sk+5][sm]=p1.y; B0[sk+6][sm]=p1.z; B0[sk+7][sm]=p1.w;
    B1[sk+0][sm]=q0.x; B1[sk+1][sm]=q0.y; B1[sk+2][sm]=q0.z; B1[sk+3][sm]=q0.w;
    B1[sk+4][sm]=q1.x; B1[sk+5][sm]=q1.y; B1[sk+6][sm]=q1.z; B1[sk+7][sm]=q1.w;
    B2[sk+0][sm]=r0.x; B2[sk+1][sm]=r0.y; B2[sk+2][sm]=r0.z; B2[sk+3][sm]=r0.w;
    B2[sk+4][sm]=r1.x; B2[sk+5][sm]=r1.y; B2[sk+6][sm]=r1.z; B2[sk+7][sm]=r1.w;
    __syncthreads();
    mma_chunk(tid, As,B0,B1,B2, aR,aZ,aN1);
  }

  // pass 2 (internal nodes): gates += red @ W_hh^T  (n-gate kept separate in aN2)
  if(!LEAF){
    #pragma unroll 1
    for(int kk=0; kk<256; kk+=32){
      float4 a0 = *(const float4*)(rrow + kk + sk);
      float4 a1 = *(const float4*)(rrow + kk + sk + 4);
      float4 p0 = *(const float4*)(w_hh + wrow          + kk + sk);
      float4 p1 = *(const float4*)(w_hh + wrow          + kk + sk + 4);
      float4 q0 = *(const float4*)(w_hh + wrow +  65536 + kk + sk);
      float4 q1 = *(const float4*)(w_hh + wrow +  65536 + kk + sk + 4);
      float4 r0 = *(const float4*)(w_hh + wrow + 131072 + kk + sk);
      float4 r1 = *(const float4*)(w_hh + wrow + 131072 + kk + sk + 4);
      __syncthreads();
      As[sk+0][sm]=a0.x; As[sk+1][sm]=a0.y; As[sk+2][sm]=a0.z; As[sk+3][sm]=a0.w;
      As[sk+4][sm]=a1.x; As[sk+5][sm]=a1.y; As[sk+6][sm]=a1.z; As[sk+7][sm]=a1.w;
      B0[sk+0][sm]=p0.x; B0[sk+1][sm]=p0.y; B0[sk+2][sm]=p0.z; B0[sk+3][sm]=p0.w;
      B0[sk+4][sm]=p1.x; B0[sk+5][sm]=p1.y; B0[sk+6][sm]=p1.z; B0[sk+7][sm]=p1.w;
      B1[sk+0][sm]=q0.x; B1[sk+1][sm]=q0.y; B1[sk+2][sm]=q0.z; B1[sk+3][sm]=q0.w;
      B1[sk+4][sm]=q1.x; B1[sk+5][sm]=q1.y; B1[sk+6][sm]=q1.z; B1[sk+7][sm]=q1.w;
      B2[sk+0][sm]=r0.x; B2[sk+1][sm]=r0.y; B2[sk+2][sm]=r0.z; B2[sk+3][sm]=r0.w;
      B2[sk+4][sm]=r1.x; B2[sk+5][sm]=r1.y; B2[sk+6][sm]=r1.z; B2[sk+7][sm]=r1.w;
      __syncthreads();
      mma_chunk(tid, As,B0,B1,B2, aR,aZ,aN2);
    }
  }

  // epilogue: GRU combine + store h (fp32)
  const int i0=(tid>>4)<<2, j0=(tid&15)<<2;
  float bir[4],bhr[4],biz[4],bhz[4],bin[4],bhn[4];
  #pragma unroll
  for(int j=0;j<4;j++){
    int col = nt*64 + j0 + j;
    bir[j]=b_ih[col];      bhr[j]=b_hh[col];
    biz[j]=b_ih[256+col];  bhz[j]=b_hh[256+col];
    bin[j]=b_ih[512+col];  bhn[j]=b_hh[512+col];
  }
  #pragma unroll
  for(int i=0;i<4;i++){
    int m = mt*64 + i0 + i;
    int b = m / cnt;
    int t = t_lo + (m - b*cnt);
    float* orow = out + ((size_t)b*T_ + t)*H_ + nt*64 + j0;
    const float* rr = red + ((size_t)b*256 + t)*256 + nt*64 + j0;
    #pragma unroll
    for(int j=0;j<4;j++){
      float rv = LEAF ? 0.f : rr[j];
      float r = sigmoidf_(aR[i][j] + bir[j] + bhr[j]);
      float z = sigmoidf_(aZ[i][j] + biz[j] + bhz[j]);
      float hn = (LEAF ? 0.f : aN2[i][j]) + bhn[j];
      float n = tanhf_(aN1[i][j] + bin[j] + r*hn);
      float h = (1.f - z)*n + z*rv;
      orow[j] = sane(h);
    }
  }
}

// msg[b,t] = GRU_rel(rel_x, h[b,t]); red[b, parent(t)] += msg. t in [t_lo, t_lo+cnt), t>=1.
__global__ __launch_bounds__(256)
void msg_kernel(const float* __restrict__ hbuf, const float* __restrict__ w_hh,
                const float* __restrict__ b_hh, const float* __restrict__ table,
                const int* __restrict__ rels, float* __restrict__ red,
                int t_lo, int cnt)
{
  __shared__ float As[32][64];
  __shared__ float B0[32][64], B1[32][64], B2[32][64];
  const int tid = threadIdx.x;
  const int mt = blockIdx.x, nt = blockIdx.y;

  const int sm = tid>>2;
  const int sk = (tid&3)<<3;
  const int gm = mt*64 + sm;
  const int sb = gm / cnt;
  const int st = t_lo + (gm - sb*cnt);
  const float* hrow = hbuf + ((size_t)sb*T_ + st)*H_;
  const size_t wrow = ((size_t)(nt*64) + sm)*256;

  float aR[4][4]={}, aZ[4][4]={}, aN[4][4]={};

  #pragma unroll 1
  for(int kk=0; kk<256; kk+=32){
    float4 a0 = *(const float4*)(hrow + kk + sk);
    float4 a1 = *(const float4*)(hrow + kk + sk + 4);
    float4 p0 = *(const float4*)(w_hh + wrow          + kk + sk);
    float4 p1 = *(const float4*)(w_hh + wrow          + kk + sk + 4);
    float4 q0 = *(const float4*)(w_hh + wrow +  65536 + kk + sk);
    float4 q1 = *(const float4*)(w_hh + wrow +  65536 + kk + sk + 4);
    float4 r0 = *(const float4*)(w_hh + wrow + 131072 + kk + sk);
    float4 r1 = *(const float4*)(w_hh + wrow + 131072 + kk + sk + 4);
    __syncthreads();
    As[sk+0][sm]=a0.x; As[sk+1][sm]=a0.y; As[sk+2][sm]=a0.z; As[sk+3][sm]=a0.w;
    As[sk+4][sm]=a1.x; As[sk+5][sm]=a1.y; As[sk+6][sm]=a1.z; As[sk+7][sm]=a1.w;
    B0[sk+0][sm]=p0.x; B0[sk+1][sm]=p0.y; B0[sk+2][sm]=p0.z; B0[sk+3][sm]=p0.w;
    B0[sk+4][sm]=p1.x; B0[sk+5][sm]=p1.y; B0[sk+6][sm]=p1.z; B0[sk+7][sm]=p1.w;
    B1[sk+0][sm]=q0.x; B1[sk+1][sm]=q0.y; B1[sk+2][sm]=q0.z; B1[sk+3][sm]=q0.w;
    B1[sk+4][sm]=q1.x; B1[sk+5][sm]=q1.y; B1[sk+6][sm]=q1.z; B1[sk+7][sm]=q1.w;
    B2[sk+0][sm]=r0.x; B2[sk+1][sm]=r0.y; B2[sk+2][sm]=r0.z; B2[sk+3][sm]=r0.w;
    B2[sk+4][sm]=r1.x; B2[sk+5][sm]=r1.y; B2[sk+6][sm]=r1.z; B2[sk+7][sm]=r1.w;
    __syncthreads();
    mma_chunk(tid, As,B0,B1,B2, aR,aZ,aN);
  }

  const int i0=(tid>>4)<<2, j0=(tid&15)<<2;
  float bhr[4],bhz[4],bhn[4];
  #pragma unroll
  for(int j=0;j<4;j++){
    int col = nt*64 + j0 + j;
    bhr[j]=b_hh[col];
    bhz[j]=b_hh[256+col];
    bhn[j]=b_hh[512+col];
  }
  #pragma unroll
  for(int i=0;i<4;i++){
    int m = mt*64 + i0 + i;
    int b = m / cnt;
    int t = t_lo + (m - b*cnt);
    int rel = rels[(size_t)b*T_ + t];
    const float* tb = table + (size_t)rel*768 + nt*64 + j0;
    const float* hr = hbuf + ((size_t)b*T_ + t)*H_ + nt*64 + j0;
    float* rd = red + ((size_t)b*256 + ((t-1)>>3))*256 + nt*64 + j0;
    #pragma unroll
    for(int j=0;j<4;j++){
      float r = sigmoidf_(tb[j]     + aR[i][j] + bhr[j]);
      float z = sigmoidf_(tb[256+j] + aZ[i][j] + bhz[j]);
      float n = tanhf_(tb[512+j] + r*(aN[i][j] + bhn[j]));
      float hv = hr[j];
      float msg = (1.f - z)*n + z*hv;
      atomicAdd(rd + j, sane(msg));
    }
  }
}

extern "C" void kernel_launch(void* const* d_in, const int* in_sizes, int n_in,
                              void* d_out, int out_size, void* d_ws, size_t ws_size,
                              hipStream_t stream)
{
  const float* embs    = (const float*)d_in[0];
  const float* rel_emb = (const float*)d_in[1];
  const float* nwih    = (const float*)d_in[2];
  const float* nwhh    = (const float*)d_in[3];
  const float* nbih    = (const float*)d_in[4];
  const float* nbhh    = (const float*)d_in[5];
  const float* rwih    = (const float*)d_in[6];
  const float* rwhh    = (const float*)d_in[7];
  const float* rbih    = (const float*)d_in[8];
  const float* rbhh    = (const float*)d_in[9];
  const int*   rels    = (const int*)d_in[11];
  float* out = (float*)d_out;

  float* red   = (float*)d_ws;                    // [B, 256, 256] fp32 mailbox sums
  float* table = red + (size_t)B_*256*256;        // [64, 768] fp32 rel gi table

  hipMemsetAsync(red, 0, (size_t)B_*256*256*sizeof(float), stream);
  table_kernel<<<dim3(192), 256, 0, stream>>>(rel_emb, rwih, rbih, table);

  // topological levels of the deterministic 8-ary heap over 2048 nodes
  const int tlo[5]  = {256, 32,  4, 1, 0};
  const int cntv[5] = {1792, 224, 28, 3, 1};

  for(int L=0; L<5; L++){
    dim3 g(cntv[L], 4);
    if(L==0)
      node_kernel<true ><<<g, 256, 0, stream>>>(embs, red, nwih, nwhh, nbih, nbhh, out, tlo[L], cntv[L]);
    else
      node_kernel<false><<<g, 256, 0, stream>>>(embs, red, nwih, nwhh, nbih, nbhh, out, tlo[L], cntv[L]);
    if(L < 4)
      msg_kernel<<<g, 256, 0, stream>>>(out, rwhh, rbhh, table, rels, red, tlo[L], cntv[L]);
  }
}

// Round 4
// 884.661 us; speedup vs baseline: 2.0677x; 2.0677x over previous
//
#include <hip/hip_runtime.h>
#include <hip/hip_bf16.h>
#include <cstdint>
#include <cstddef>

#define B_ 64
#define T_ 2048

typedef unsigned short ushort_t;
typedef __attribute__((ext_vector_type(8))) short bf16x8;   // 8 bf16 (4 VGPRs)
typedef __attribute__((ext_vector_type(4))) float f32x4;    // MFMA C/D

__device__ __forceinline__ float sigmoidf_(float x){ return 1.f/(1.f+__expf(-x)); }
__device__ __forceinline__ float tanhf_(float x){
  x = fminf(fmaxf(x,-15.f),15.f);
  float e = __expf(2.f*x);
  return (e-1.f)/(e+1.f);
}

// RNE fp32->bf16 pair packed into one dword
__device__ __forceinline__ unsigned f2b_pair(float lo, float hi){
  unsigned a = __float_as_uint(lo), b = __float_as_uint(hi);
  a += 0x7FFFu + ((a>>16)&1u);
  b += 0x7FFFu + ((b>>16)&1u);
  return (a>>16) | (b & 0xFFFF0000u);
}
__device__ __forceinline__ uint4 pack8(float4 x, float4 y){
  uint4 v;
  v.x = f2b_pair(x.x, x.y);
  v.y = f2b_pair(x.z, x.w);
  v.z = f2b_pair(y.x, y.y);
  v.w = f2b_pair(y.z, y.w);
  return v;
}

// rel_table[r][j] = rel_emb[r] . rel_w_ih[j] + rel_b_ih[j], r<64, j<768  (fp32)
__global__ __launch_bounds__(256)
void table_kernel(const float* __restrict__ rel_emb, const float* __restrict__ w_ih,
                  const float* __restrict__ b_ih, float* __restrict__ table)
{
  int idx = blockIdx.x*256 + threadIdx.x;   // < 64*768
  int r = idx/768, j = idx - r*768;
  const float* e = rel_emb + (size_t)r*256;
  const float* w = w_ih   + (size_t)j*256;
  float acc = 0.f;
  for(int k=0;k<256;k+=4){
    float4 ev = *(const float4*)(e+k);
    float4 wv = *(const float4*)(w+k);
    acc = fmaf(ev.x,wv.x,acc); acc = fmaf(ev.y,wv.y,acc);
    acc = fmaf(ev.z,wv.z,acc); acc = fmaf(ev.w,wv.w,acc);
  }
  table[idx] = acc + b_ih[j];
}

// convert the three 768x256 weight matrices to bf16 (row-major, K contiguous)
__global__ __launch_bounds__(256)
void wcvt_kernel(const float* __restrict__ a, const float* __restrict__ b, const float* __restrict__ c,
                 ushort_t* __restrict__ oa, ushort_t* __restrict__ ob, ushort_t* __restrict__ oc)
{
  int i = blockIdx.x*256 + threadIdx.x;     // < 3*24576
  int seg = i / 24576;
  int off = (i - seg*24576) * 8;
  const float* s; ushort_t* d;
  if(seg==0){ s=a; d=oa; } else if(seg==1){ s=b; d=ob; } else { s=c; d=oc; }
  float4 x = *(const float4*)(s+off), y = *(const float4*)(s+off+4);
  *(uint4*)(d+off) = pack8(x,y);
}

// ---------------------------------------------------------------------------
// MFMA GEMM+GRU kernels.
// Tile: 128 rows x (3 gates x 64 cols).  Grid = (ceil(M/128), 4).
// LDS: As[128][32] bf16 (A rows, k-contig), Bs[192][32] bf16 (W rows: gate*64+n).
// Wave w owns rows w*32..w*32+31: 2 m-tiles x 12 n-tiles of 16x16x32 MFMA.
// C/D layout (m89-verified): col = lane&15, row = (lane>>4)*4 + reg.
// ---------------------------------------------------------------------------

template<bool LEAF>
__global__ __launch_bounds__(256)
void node_mfma(const float* __restrict__ embs, const float* __restrict__ red,
               const ushort_t* __restrict__ wih, const ushort_t* __restrict__ whh,
               const float* __restrict__ b_ih, const float* __restrict__ b_hh,
               float* __restrict__ out, int t_lo, unsigned cnt, unsigned Mtot)
{
  __shared__ ushort_t As[128][32];
  __shared__ ushort_t Bs[192][32];
  const int tid  = threadIdx.x;
  const unsigned Mbase = blockIdx.x*128u;
  const int nb   = blockIdx.y;          // 64-col block within each gate
  const int lane = tid & 63, w = tid >> 6;
  const int quad = lane >> 4, cl = lane & 15;

  // staging assignment: thread -> (row tid>>2 [+64], 8 k's at (tid&3)*8)
  const int srow = tid >> 2;
  const int g8   = (tid & 3) * 8;
  unsigned r0 = Mbase + srow;      if(r0 > Mtot-1) r0 = Mtot-1;
  unsigned r1 = Mbase + srow + 64; if(r1 > Mtot-1) r1 = Mtot-1;
  unsigned b0v = r0 / cnt, t0v = (unsigned)t_lo + (r0 - b0v*cnt);
  unsigned b1v = r1 / cnt, t1v = (unsigned)t_lo + (r1 - b1v*cnt);
  const float* x0p = embs + ((size_t)b0v*T_ + t0v)*256 + g8;
  const float* x1p = embs + ((size_t)b1v*T_ + t1v)*256 + g8;
  const float* rd0p = red + ((size_t)b0v*256 + t0v)*256 + g8;
  const float* rd1p = red + ((size_t)b1v*256 + t1v)*256 + g8;
  // B staging: issue e stages LDS rows e*64+srow  <- W row e*256 + nb*64 + srow
  const size_t woff0 = ((size_t)(0*256 + nb*64 + srow))*256 + g8;
  const size_t woff1 = ((size_t)(1*256 + nb*64 + srow))*256 + g8;
  const size_t woff2 = ((size_t)(2*256 + nb*64 + srow))*256 + g8;

  f32x4 acc[2][12];
  f32x4 accN2[2][4];
  const f32x4 zz = {0.f,0.f,0.f,0.f};
  #pragma unroll
  for(int i=0;i<2;i++){
    #pragma unroll
    for(int j=0;j<12;j++) acc[i][j] = zz;
    #pragma unroll
    for(int j=0;j<4;j++) accN2[i][j] = zz;
  }

  const int npass = LEAF ? 1 : 2;
  for(int pass=0; pass<npass; pass++){
    const float* a0 = pass ? rd0p : x0p;
    const float* a1 = pass ? rd1p : x1p;
    const ushort_t* W = pass ? whh : wih;
    #pragma unroll 1
    for(int kk=0; kk<256; kk+=32){
      float4 ax0 = *(const float4*)(a0 + kk);
      float4 ay0 = *(const float4*)(a0 + kk + 4);
      float4 ax1 = *(const float4*)(a1 + kk);
      float4 ay1 = *(const float4*)(a1 + kk + 4);
      uint4 w0 = *(const uint4*)(W + woff0 + kk);
      uint4 w1 = *(const uint4*)(W + woff1 + kk);
      uint4 w2 = *(const uint4*)(W + woff2 + kk);
      __syncthreads();
      *(uint4*)&As[srow     ][g8] = pack8(ax0, ay0);
      *(uint4*)&As[srow + 64][g8] = pack8(ax1, ay1);
      *(uint4*)&Bs[srow      ][g8] = w0;
      *(uint4*)&Bs[srow +  64][g8] = w1;
      *(uint4*)&Bs[srow + 128][g8] = w2;
      __syncthreads();
      bf16x8 af0 = *(const bf16x8*)&As[w*32      + cl][quad*8];
      bf16x8 af1 = *(const bf16x8*)&As[w*32 + 16 + cl][quad*8];
      #pragma unroll
      for(int j=0;j<12;j++){
        bf16x8 bfj = *(const bf16x8*)&Bs[j*16 + cl][quad*8];
        if(!LEAF && pass==1 && j>=8){
          accN2[0][j-8] = __builtin_amdgcn_mfma_f32_16x16x32_bf16(af0, bfj, accN2[0][j-8], 0,0,0);
          accN2[1][j-8] = __builtin_amdgcn_mfma_f32_16x16x32_bf16(af1, bfj, accN2[1][j-8], 0,0,0);
        } else {
          acc[0][j] = __builtin_amdgcn_mfma_f32_16x16x32_bf16(af0, bfj, acc[0][j], 0,0,0);
          acc[1][j] = __builtin_amdgcn_mfma_f32_16x16x32_bf16(af1, bfj, acc[1][j], 0,0,0);
        }
      }
    }
  }

  // epilogue: GRU combine, fp32 store (clamped duplicate rows write same value)
  float bir[4],biz[4],bin[4],bhr[4],bhz[4],bhn[4];
  #pragma unroll
  for(int c=0;c<4;c++){
    int col = nb*64 + c*16 + cl;
    bir[c]=b_ih[col]; biz[c]=b_ih[256+col]; bin[c]=b_ih[512+col];
    bhr[c]=b_hh[col]; bhz[c]=b_hh[256+col]; bhn[c]=b_hh[512+col];
  }
  #pragma unroll
  for(int i=0;i<2;i++){
    #pragma unroll
    for(int r=0;r<4;r++){
      unsigned gm = Mbase + (unsigned)(w*32 + i*16 + quad*4 + r);
      if(gm > Mtot-1) gm = Mtot-1;
      unsigned b = gm / cnt, t = (unsigned)t_lo + (gm - b*cnt);
      float* orow = out + ((size_t)b*T_ + t)*256;
      const float* rr = red + ((size_t)b*256 + t)*256;
      #pragma unroll
      for(int c=0;c<4;c++){
        int col = nb*64 + c*16 + cl;
        float gr = acc[i][c][r]   + bir[c] + bhr[c];
        float gz = acc[i][4+c][r] + biz[c] + bhz[c];
        float gni = acc[i][8+c][r] + bin[c];
        float hn  = (LEAF ? 0.f : accN2[i][c][r]) + bhn[c];
        float rg = sigmoidf_(gr);
        float zg = sigmoidf_(gz);
        float ng = tanhf_(gni + rg*hn);
        float rv = LEAF ? 0.f : rr[col];
        orow[col] = (1.f-zg)*ng + zg*rv;
      }
    }
  }
}

// msg: gates = table[rel] (gi) + h @ rel_w_hh^T + rel_b_hh; red[parent] += msg
__global__ __launch_bounds__(256)
void msg_mfma(const float* __restrict__ hbuf, const ushort_t* __restrict__ wbf,
              const float* __restrict__ b_hh, const float* __restrict__ table,
              const int* __restrict__ rels, float* __restrict__ red,
              int t_lo, unsigned cnt, unsigned Mtot)
{
  __shared__ ushort_t As[128][32];
  __shared__ ushort_t Bs[192][32];
  const int tid  = threadIdx.x;
  const unsigned Mbase = blockIdx.x*128u;
  const int nb   = blockIdx.y;
  const int lane = tid & 63, w = tid >> 6;
  const int quad = lane >> 4, cl = lane & 15;

  const int srow = tid >> 2;
  const int g8   = (tid & 3) * 8;
  unsigned r0 = Mbase + srow;      if(r0 > Mtot-1) r0 = Mtot-1;
  unsigned r1 = Mbase + srow + 64; if(r1 > Mtot-1) r1 = Mtot-1;
  unsigned b0v = r0 / cnt, t0v = (unsigned)t_lo + (r0 - b0v*cnt);
  unsigned b1v = r1 / cnt, t1v = (unsigned)t_lo + (r1 - b1v*cnt);
  const float* a0 = hbuf + ((size_t)b0v*T_ + t0v)*256 + g8;
  const float* a1 = hbuf + ((size_t)b1v*T_ + t1v)*256 + g8;
  const size_t woff0 = ((size_t)(0*256 + nb*64 + srow))*256 + g8;
  const size_t woff1 = ((size_t)(1*256 + nb*64 + srow))*256 + g8;
  const size_t woff2 = ((size_t)(2*256 + nb*64 + srow))*256 + g8;

  f32x4 acc[2][12];
  const f32x4 zz = {0.f,0.f,0.f,0.f};
  #pragma unroll
  for(int i=0;i<2;i++)
    #pragma unroll
    for(int j=0;j<12;j++) acc[i][j] = zz;

  #pragma unroll 1
  for(int kk=0; kk<256; kk+=32){
    float4 ax0 = *(const float4*)(a0 + kk);
    float4 ay0 = *(const float4*)(a0 + kk + 4);
    float4 ax1 = *(const float4*)(a1 + kk);
    float4 ay1 = *(const float4*)(a1 + kk + 4);
    uint4 w0 = *(const uint4*)(wbf + woff0 + kk);
    uint4 w1 = *(const uint4*)(wbf + woff1 + kk);
    uint4 w2 = *(const uint4*)(wbf + woff2 + kk);
    __syncthreads();
    *(uint4*)&As[srow     ][g8] = pack8(ax0, ay0);
    *(uint4*)&As[srow + 64][g8] = pack8(ax1, ay1);
    *(uint4*)&Bs[srow      ][g8] = w0;
    *(uint4*)&Bs[srow +  64][g8] = w1;
    *(uint4*)&Bs[srow + 128][g8] = w2;
    __syncthreads();
    bf16x8 af0 = *(const bf16x8*)&As[w*32      + cl][quad*8];
    bf16x8 af1 = *(const bf16x8*)&As[w*32 + 16 + cl][quad*8];
    #pragma unroll
    for(int j=0;j<12;j++){
      bf16x8 bfj = *(const bf16x8*)&Bs[j*16 + cl][quad*8];
      acc[0][j] = __builtin_amdgcn_mfma_f32_16x16x32_bf16(af0, bfj, acc[0][j], 0,0,0);
      acc[1][j] = __builtin_amdgcn_mfma_f32_16x16x32_bf16(af1, bfj, acc[1][j], 0,0,0);
    }
  }

  float bhr[4],bhz[4],bhn[4];
  #pragma unroll
  for(int c=0;c<4;c++){
    int col = nb*64 + c*16 + cl;
    bhr[c]=b_hh[col]; bhz[c]=b_hh[256+col]; bhn[c]=b_hh[512+col];
  }
  #pragma unroll
  for(int i=0;i<2;i++){
    #pragma unroll
    for(int r=0;r<4;r++){
      unsigned gm = Mbase + (unsigned)(w*32 + i*16 + quad*4 + r);
      bool ok = (gm < Mtot);               // guard: clamped duplicates must not atomic-add
      if(gm > Mtot-1) gm = Mtot-1;
      unsigned b = gm / cnt, t = (unsigned)t_lo + (gm - b*cnt);
      int rel = rels[(size_t)b*T_ + t];
      const float* tb = table + (size_t)rel*768;
      const float* hr = hbuf + ((size_t)b*T_ + t)*256;
      float* rd = red + ((size_t)b*256 + ((t-1)>>3))*256;
      #pragma unroll
      for(int c=0;c<4;c++){
        int col = nb*64 + c*16 + cl;
        float gr  = tb[col]     + acc[i][c][r]   + bhr[c];
        float gz  = tb[256+col] + acc[i][4+c][r] + bhz[c];
        float gnh = acc[i][8+c][r] + bhn[c];
        float rg = sigmoidf_(gr);
        float zg = sigmoidf_(gz);
        float ng = tanhf_(tb[512+col] + rg*gnh);
        float msg = (1.f-zg)*ng + zg*hr[col];
        if(ok) atomicAdd(rd + col, msg);
      }
    }
  }
}

extern "C" void kernel_launch(void* const* d_in, const int* in_sizes, int n_in,
                              void* d_out, int out_size, void* d_ws, size_t ws_size,
                              hipStream_t stream)
{
  const float* embs    = (const float*)d_in[0];
  const float* rel_emb = (const float*)d_in[1];
  const float* nwih    = (const float*)d_in[2];
  const float* nwhh    = (const float*)d_in[3];
  const float* nbih    = (const float*)d_in[4];
  const float* nbhh    = (const float*)d_in[5];
  const float* rwih    = (const float*)d_in[6];
  const float* rwhh    = (const float*)d_in[7];
  const float* rbih    = (const float*)d_in[8];
  const float* rbhh    = (const float*)d_in[9];
  const int*   rels    = (const int*)d_in[11];
  float* out = (float*)d_out;

  float* red   = (float*)d_ws;              // [64][256][256] fp32 mailbox
  float* table = red + (size_t)4194304;     // [64][768] fp32
  ushort_t* wih_bf  = (ushort_t*)(table + 49152);
  ushort_t* whh_bf  = wih_bf + 196608;
  ushort_t* rwhh_bf = whh_bf + 196608;

  hipMemsetAsync(red, 0, (size_t)4194304*4, stream);
  table_kernel<<<dim3(192), 256, 0, stream>>>(rel_emb, rwih, rbih, table);
  wcvt_kernel<<<dim3(288), 256, 0, stream>>>(nwih, nwhh, rwhh, wih_bf, whh_bf, rwhh_bf);

  // topological levels of the deterministic 8-ary heap over 2048 nodes
  const int      tlo[5] = {256, 32, 4, 1, 0};
  const unsigned cntv[5]= {1792, 224, 28, 3, 1};
  const unsigned Mv[5]  = {114688, 14336, 1792, 192, 64};

  for(int L=0; L<5; L++){
    dim3 g((Mv[L]+127)/128, 4);
    if(L==0)
      node_mfma<true ><<<g, 256, 0, stream>>>(embs, red, wih_bf, whh_bf, nbih, nbhh, out, tlo[L], cntv[L], Mv[L]);
    else
      node_mfma<false><<<g, 256, 0, stream>>>(embs, red, wih_bf, whh_bf, nbih, nbhh, out, tlo[L], cntv[L], Mv[L]);
    if(L < 4)
      msg_mfma<<<g, 256, 0, stream>>>(out, rwhh_bf, rbhh, table, rels, red, tlo[L], cntv[L], Mv[L]);
  }
}